// Round 1
// baseline (1149.309 us; speedup 1.0000x reference)
//
#include <hip/hip_runtime.h>
#include <hip/hip_bf16.h>
#include <stdint.h>

typedef __attribute__((ext_vector_type(4))) float f32x4;
typedef __attribute__((ext_vector_type(8))) short short8;
typedef unsigned int u32;
typedef unsigned short ushort_t;

#define L_DIM 2048
#define B_DIM 32
#define D_DIM 512
#define M_DIM (L_DIM * B_DIM)       // 65536
#define N_DIM (3 * D_DIM)           // 1536
#define K_DIM D_DIM                 // 512
#define BD    (B_DIM * D_DIM)       // 16384
#define PLANE ((size_t)M_DIM * D_DIM)  // 33554432 elems per U plane

// ---------- helpers ----------
__device__ inline ushort_t f2bf(float f) {
    uint32_t u = __float_as_uint(f);
    u += 0x7FFFu + ((u >> 16) & 1u);   // RNE
    return (ushort_t)(u >> 16);
}
__device__ inline float b2f(ushort_t h) {
    return __uint_as_float(((uint32_t)h) << 16);
}
__device__ inline void gll16(const ushort_t* g, ushort_t* l) {
    __builtin_amdgcn_global_load_lds(
        (const __attribute__((address_space(1))) u32*)g,
        (__attribute__((address_space(3))) u32*)l,
        16, 0, 0);
}

// ---------- kernel 1: x (f32) -> xb (bf16) ----------
__global__ void k_convert_x(const float4* __restrict__ x, ushort4* __restrict__ xb) {
    int i = blockIdx.x * blockDim.x + threadIdx.x;
    int stride = gridDim.x * blockDim.x;
    const int n4 = M_DIM * D_DIM / 4;   // 8388608
    for (; i < n4; i += stride) {
        float4 v = x[i];
        ushort4 o;
        o.x = f2bf(v.x); o.y = f2bf(v.y); o.z = f2bf(v.z); o.w = f2bf(v.w);
        xb[i] = o;
    }
}

// ---------- kernel 2: weight (D,3D) f32 -> wt [N][K] bf16, gate-deinterleaved ----------
// wt row n = g*512 + d  holds weight[:, d*3+g]  (K contiguous per row)
__global__ void k_prep_w(const float* __restrict__ w, ushort_t* __restrict__ wt) {
    int idx = blockIdx.x * blockDim.x + threadIdx.x;
    if (idx >= N_DIM * K_DIM) return;
    int k = idx & 511;
    int n = idx >> 9;
    int dcol = (n & 511) * 3 + (n >> 9);
    wt[idx] = f2bf(w[(size_t)k * N_DIM + dcol]);
}

// ---------- kernel 3: GEMM  U[g][r*512+d] = sum_k xb[r,k]*wt[g*512+d,k] (+bias) ----------
// m97 structure: 128x128 tile, BK=64, 4 waves (2x2), 16x16x32 bf16 MFMA,
// global_load_lds width=16, XOR-swizzled LDS (rule #21: inverse-swz source + swz read).
__global__ __launch_bounds__(256) void k_gemm(
    const ushort_t* __restrict__ Ag,   // [M,K] bf16
    const ushort_t* __restrict__ Wt,   // [N,K] bf16
    const float*    __restrict__ bias, // [2D]
    ushort_t*       __restrict__ U)    // 3 planes of [M,D] bf16
{
    __shared__ ushort_t As[128 * 64];
    __shared__ ushort_t Bs[128 * 64];
    const int tid  = threadIdx.x;
    const int lane = tid & 63;
    const int w    = tid >> 6;
    const int wm   = w >> 1, wn = w & 1;
    const int bn0  = blockIdx.x * 128;   // N offset
    const int bm0  = blockIdx.y * 128;   // M offset

    f32x4 acc[4][4] = {};

    for (int kt = 0; kt < K_DIM / 64; ++kt) {
        if (kt) __syncthreads();
        // stage: 1024 chunks of 16B per tile; thread handles chunks tid, tid+256, ...
        // logical LDS layout: row-major [128 rows][64 bf16] (128B rows), chunk = 16B.
        // swizzle: LDS byte q belongs to logical byte q ^ ((row&7)<<4); dest stays linear,
        // so source chunk-in-row is XORed instead.
#pragma unroll
        for (int it = 0; it < 4; ++it) {
            int c   = it * 256 + tid;
            int row = c >> 3;
            int cin = (c & 7) ^ (row & 7);
            const ushort_t* ga = Ag + (size_t)(bm0 + row) * K_DIM + kt * 64 + cin * 8;
            const ushort_t* gb = Wt + (size_t)(bn0 + row) * K_DIM + kt * 64 + cin * 8;
            int chunkbase = it * 256 + w * 64;   // wave-uniform
            gll16(ga, As + chunkbase * 8);
            gll16(gb, Bs + chunkbase * 8);
        }
        __syncthreads();
#pragma unroll
        for (int kk = 0; kk < 2; ++kk) {
            short8 af[4], bfr[4];
#pragma unroll
            for (int m = 0; m < 4; ++m) {
                int row  = wm * 64 + m * 16 + (lane & 15);
                int byte = (row * 128 + kk * 64 + ((lane >> 4) * 16)) ^ ((row & 7) << 4);
                af[m] = *(const short8*)((const char*)As + byte);
            }
#pragma unroll
            for (int n = 0; n < 4; ++n) {
                int row  = wn * 64 + n * 16 + (lane & 15);
                int byte = (row * 128 + kk * 64 + ((lane >> 4) * 16)) ^ ((row & 7) << 4);
                bfr[n] = *(const short8*)((const char*)Bs + byte);
            }
#pragma unroll
            for (int m = 0; m < 4; ++m)
#pragma unroll
                for (int n = 0; n < 4; ++n)
                    acc[m][n] = __builtin_amdgcn_mfma_f32_16x16x32_bf16(
                        af[m], bfr[n], acc[m][n], 0, 0, 0);
        }
    }

    // epilogue: C/D layout col=lane&15, row=(lane>>4)*4+reg  (m89-verified)
    const int g  = bn0 >> 9;               // plane (block fully inside one plane)
    const int db = (bn0 & 511) + wn * 64;  // d base in plane
    ushort_t* Up = U + (size_t)g * PLANE;
#pragma unroll
    for (int n = 0; n < 4; ++n) {
        int col = db + n * 16 + (lane & 15);
        float ba = 0.f;
        if (g) ba = bias[(g - 1) * 512 + col];
#pragma unroll
        for (int m = 0; m < 4; ++m) {
            int row0 = bm0 + wm * 64 + m * 16 + ((lane >> 4) * 4);
#pragma unroll
            for (int q = 0; q < 4; ++q) {
                Up[(size_t)(row0 + q) * D_DIM + col] = f2bf(acc[m][n][q] + ba);
            }
        }
    }
}

// ---------- kernel 4: sequential scan over L, 16384 independent chains ----------
__global__ __launch_bounds__(64) void k_scan(
    const ushort_t* __restrict__ U,    // 3 planes
    const ushort_t* __restrict__ xb,
    const float*    __restrict__ wc,   // weight_c [2D]
    const float*    __restrict__ cin,  // c_init [B,D]
    float*          __restrict__ out)  // h [L,B,D] then c_last [B,D]
{
    const int chain = blockIdx.x * 64 + threadIdx.x;
    const int d = chain & 511;
    const float fw = wc[d], rw = wc[512 + d];
    float c = cin[chain];

    const ushort_t* p0 = U + chain;
    const ushort_t* p1 = U + PLANE + chain;
    const ushort_t* p2 = U + 2 * PLANE + chain;
    const ushort_t* px = xb + chain;
    float* ho = out + chain;

    constexpr int PF = 8;   // prefetch depth (static ring, rule #20)
    ushort_t s0[PF], s1[PF], s2[PF], sx[PF];
#pragma unroll
    for (int s = 0; s < PF; ++s) {
        s0[s] = p0[(size_t)s * BD];
        s1[s] = p1[(size_t)s * BD];
        s2[s] = p2[(size_t)s * BD];
        sx[s] = px[(size_t)s * BD];
    }
    for (int t0 = 0; t0 < L_DIM; t0 += PF) {
#pragma unroll
        for (int s = 0; s < PF; ++s) {
            const int t = t0 + s;
            float u0 = b2f(s0[s]), u1 = b2f(s1[s]), u2 = b2f(s2[s]), xf = b2f(sx[s]);
            const int tn = t + PF;
            if (tn < L_DIM) {   // uniform branch; issue next loads early
                s0[s] = p0[(size_t)tn * BD];
                s1[s] = p1[(size_t)tn * BD];
                s2[s] = p2[(size_t)tn * BD];
                sx[s] = px[(size_t)tn * BD];
            }
            float f = __builtin_amdgcn_rcpf(1.f + __expf(-(u1 + c * fw)));
            float r = __builtin_amdgcn_rcpf(1.f + __expf(-(u2 + c * rw)));
            c = u0 + (c - u0) * f;
            ho[(size_t)t * BD] = xf + (c - xf) * r;
        }
    }
    out[(size_t)L_DIM * BD + chain] = c;
}

// ---------- launch ----------
extern "C" void kernel_launch(void* const* d_in, const int* in_sizes, int n_in,
                              void* d_out, int out_size, void* d_ws, size_t ws_size,
                              hipStream_t stream) {
    const float* x      = (const float*)d_in[0];
    const float* weight = (const float*)d_in[1];
    const float* wc     = (const float*)d_in[2];
    const float* bias   = (const float*)d_in[3];
    const float* cinit  = (const float*)d_in[4];
    float* out = (float*)d_out;

    // ws layout (bf16 elems): xb[33554432] | U0|U1|U2 [3*33554432] | wt[786432]
    // total 270,008,320 bytes
    ushort_t* ws = (ushort_t*)d_ws;
    ushort_t* xb = ws;
    ushort_t* U  = ws + PLANE;           // 3 contiguous planes
    ushort_t* wt = ws + 4 * PLANE;

    k_convert_x<<<4096, 256, 0, stream>>>((const float4*)x, (ushort4*)xb);
    k_prep_w<<<(N_DIM * K_DIM) / 256, 256, 0, stream>>>(weight, wt);
    dim3 grid(N_DIM / 128, M_DIM / 128);   // (12, 512)
    k_gemm<<<grid, 256, 0, stream>>>(xb, wt, bias, U);
    k_scan<<<BD / 64, 64, 0, stream>>>(U, xb, wc, cinit, out);
}

// Round 2
// 303.639 us; speedup vs baseline: 3.7851x; 3.7851x over previous
//
#include <hip/hip_runtime.h>
#include <hip/hip_bf16.h>
#include <stdint.h>

typedef __attribute__((ext_vector_type(4))) float f32x4;
typedef __attribute__((ext_vector_type(8))) short short8;
typedef unsigned int u32;
typedef unsigned short ushort_t;

#define L_DIM 2048
#define B_DIM 32
#define D_DIM 512
#define M_DIM (L_DIM * B_DIM)       // 65536
#define N_DIM (3 * D_DIM)           // 1536
#define K_DIM D_DIM                 // 512
#define BD    (B_DIM * D_DIM)       // 16384
#define PLANE ((size_t)M_DIM * D_DIM)  // 33554432 elems per U plane
#define CHUNK 32
#define NCHUNK (L_DIM / CHUNK)      // 64

// ---------- helpers ----------
__device__ inline ushort_t f2bf(float f) {
    uint32_t u = __float_as_uint(f);
    u += 0x7FFFu + ((u >> 16) & 1u);   // RNE
    return (ushort_t)(u >> 16);
}
__device__ inline float b2f(ushort_t h) {
    return __uint_as_float(((uint32_t)h) << 16);
}
__device__ inline void gll16(const ushort_t* g, ushort_t* l) {
    __builtin_amdgcn_global_load_lds(
        (const __attribute__((address_space(1))) u32*)g,
        (__attribute__((address_space(3))) u32*)l,
        16, 0, 0);
}
__device__ inline void gll4(const ushort_t* g, ushort_t* l) {
    __builtin_amdgcn_global_load_lds(
        (const __attribute__((address_space(1))) u32*)g,
        (__attribute__((address_space(3))) u32*)l,
        4, 0, 0);
}

// ---------- kernel 1: x (f32) -> xb (bf16) ----------
__global__ void k_convert_x(const float4* __restrict__ x, ushort4* __restrict__ xb) {
    int i = blockIdx.x * blockDim.x + threadIdx.x;
    int stride = gridDim.x * blockDim.x;
    const int n4 = M_DIM * D_DIM / 4;   // 8388608
    for (; i < n4; i += stride) {
        float4 v = x[i];
        ushort4 o;
        o.x = f2bf(v.x); o.y = f2bf(v.y); o.z = f2bf(v.z); o.w = f2bf(v.w);
        xb[i] = o;
    }
}

// ---------- kernel 2: weight (D,3D) f32 -> wt [N][K] bf16, gate-deinterleaved ----------
__global__ void k_prep_w(const float* __restrict__ w, ushort_t* __restrict__ wt) {
    int idx = blockIdx.x * blockDim.x + threadIdx.x;
    if (idx >= N_DIM * K_DIM) return;
    int k = idx & 511;
    int n = idx >> 9;
    int dcol = (n & 511) * 3 + (n >> 9);
    wt[idx] = f2bf(w[(size_t)k * N_DIM + dcol]);
}

// ---------- kernel 3: GEMM (unchanged from round 1, verified) ----------
__global__ __launch_bounds__(256) void k_gemm(
    const ushort_t* __restrict__ Ag,   // [M,K] bf16
    const ushort_t* __restrict__ Wt,   // [N,K] bf16
    const float*    __restrict__ bias, // [2D]
    ushort_t*       __restrict__ U)    // 3 planes of [M,D] bf16
{
    __shared__ ushort_t As[128 * 64];
    __shared__ ushort_t Bs[128 * 64];
    const int tid  = threadIdx.x;
    const int lane = tid & 63;
    const int w    = tid >> 6;
    const int wm   = w >> 1, wn = w & 1;
    const int bn0  = blockIdx.x * 128;   // N offset
    const int bm0  = blockIdx.y * 128;   // M offset

    f32x4 acc[4][4] = {};

    for (int kt = 0; kt < K_DIM / 64; ++kt) {
        if (kt) __syncthreads();
#pragma unroll
        for (int it = 0; it < 4; ++it) {
            int c   = it * 256 + tid;
            int row = c >> 3;
            int cin = (c & 7) ^ (row & 7);
            const ushort_t* ga = Ag + (size_t)(bm0 + row) * K_DIM + kt * 64 + cin * 8;
            const ushort_t* gb = Wt + (size_t)(bn0 + row) * K_DIM + kt * 64 + cin * 8;
            int chunkbase = it * 256 + w * 64;   // wave-uniform
            gll16(ga, As + chunkbase * 8);
            gll16(gb, Bs + chunkbase * 8);
        }
        __syncthreads();
#pragma unroll
        for (int kk = 0; kk < 2; ++kk) {
            short8 af[4], bfr[4];
#pragma unroll
            for (int m = 0; m < 4; ++m) {
                int row  = wm * 64 + m * 16 + (lane & 15);
                int byte = (row * 128 + kk * 64 + ((lane >> 4) * 16)) ^ ((row & 7) << 4);
                af[m] = *(const short8*)((const char*)As + byte);
            }
#pragma unroll
            for (int n = 0; n < 4; ++n) {
                int row  = wn * 64 + n * 16 + (lane & 15);
                int byte = (row * 128 + kk * 64 + ((lane >> 4) * 16)) ^ ((row & 7) << 4);
                bfr[n] = *(const short8*)((const char*)Bs + byte);
            }
#pragma unroll
            for (int m = 0; m < 4; ++m)
#pragma unroll
                for (int n = 0; n < 4; ++n)
                    acc[m][n] = __builtin_amdgcn_mfma_f32_16x16x32_bf16(
                        af[m], bfr[n], acc[m][n], 0, 0, 0);
        }
    }

    const int g  = bn0 >> 9;               // plane (block fully inside one plane)
    const int db = (bn0 & 511) + wn * 64;  // d base in plane
    ushort_t* Up = U + (size_t)g * PLANE;
#pragma unroll
    for (int n = 0; n < 4; ++n) {
        int col = db + n * 16 + (lane & 15);
        float ba = 0.f;
        if (g) ba = bias[(g - 1) * 512 + col];
#pragma unroll
        for (int m = 0; m < 4; ++m) {
            int row0 = bm0 + wm * 64 + m * 16 + ((lane >> 4) * 4);
#pragma unroll
            for (int q = 0; q < 4; ++q) {
                Up[(size_t)(row0 + q) * D_DIM + col] = f2bf(acc[m][n][q] + ba);
            }
        }
    }
}

// ---------- kernel 4: producer/consumer sequential scan ----------
// wave 0: streams u0,u1,u2,x planes into double-buffered LDS ring via
//         global_load_lds (independent loads -> full MLP, latency-immune)
// wave 1: serial recurrence out of LDS, coalesced h stores
__global__ __launch_bounds__(128) void k_scan(
    const ushort_t* __restrict__ U,    // 3 planes [t*32+b][d]
    const ushort_t* __restrict__ xb,   // [t*32+b][d]
    const float*    __restrict__ wc,   // weight_c [2D]
    const float*    __restrict__ cin,  // c_init [B,D]
    float*          __restrict__ out)  // h [L,B,D] f32, then c_last [B,D]
{
    __shared__ ushort_t ring[4][2][CHUNK][64];   // 32 KiB

    const int tid  = threadIdx.x;
    const int lane = tid & 63;
    const int wid  = tid >> 6;
    const int cb   = blockIdx.x * 64;            // chain base

    // ---- producer state (wave 0) ----
    const int half = lane >> 5;                  // which step of the 2-step pair
    const int coff = (lane & 31) * 2;            // 2 chains per lane (4B)
    const ushort_t* s0 = U + cb + coff;
    const ushort_t* s1 = U + PLANE + cb + coff;
    const ushort_t* s2 = U + 2 * PLANE + cb + coff;
    const ushort_t* s3 = xb + cb + coff;

    // ---- consumer state (wave 1) ----
    const int chain = cb + lane;
    const int d     = chain & 511;
    float fw = 0.f, rw = 0.f, c = 0.f;
    if (wid == 1) { fw = wc[d]; rw = wc[512 + d]; c = cin[chain]; }
    float* ho = out + chain;

#define PRODUCE(CK, NB)                                                        \
    do {                                                                       \
        const size_t t0_ = (size_t)(CK) * CHUNK + half;                        \
        _Pragma("unroll")                                                      \
        for (int j = 0; j < 16; ++j) {                                         \
            gll4(s0 + (t0_ + 2 * j) * BD, &ring[0][NB][2 * j][0]);             \
            gll4(s1 + (t0_ + 2 * j) * BD, &ring[1][NB][2 * j][0]);             \
            gll4(s2 + (t0_ + 2 * j) * BD, &ring[2][NB][2 * j][0]);             \
            gll4(s3 + (t0_ + 2 * j) * BD, &ring[3][NB][2 * j][0]);             \
        }                                                                      \
    } while (0)

#define LG(P, BUF, g0)                                                         \
    {                                                                          \
        _Pragma("unroll")                                                      \
        for (int s = 0; s < 8; ++s) {                                          \
            P##0[s] = ring[0][BUF][(g0) + s][lane];                            \
            P##1[s] = ring[1][BUF][(g0) + s][lane];                            \
            P##2[s] = ring[2][BUF][(g0) + s][lane];                            \
            P##x[s] = ring[3][BUF][(g0) + s][lane];                            \
        }                                                                      \
    }

#define CG(P, tb, g0)                                                          \
    {                                                                          \
        _Pragma("unroll")                                                      \
        for (int s = 0; s < 8; ++s) {                                          \
            float u0 = b2f(P##0[s]), u1 = b2f(P##1[s]);                        \
            float u2 = b2f(P##2[s]), xf = b2f(P##x[s]);                        \
            float f = __builtin_amdgcn_rcpf(1.f + __expf(-(u1 + c * fw)));     \
            float r = __builtin_amdgcn_rcpf(1.f + __expf(-(u2 + c * rw)));     \
            c = u0 + (c - u0) * f;                                             \
            ho[(size_t)((tb) + (g0) + s) * BD] = xf + (c - xf) * r;            \
        }                                                                      \
    }

    if (wid == 0) PRODUCE(0, 0);
    __syncthreads();

    for (int ck = 0; ck < NCHUNK; ++ck) {
        if (wid == 0) {
            if (ck + 1 < NCHUNK) {
                const int nb = (ck + 1) & 1;
                PRODUCE(ck + 1, nb);
            }
        } else {
            const int buf = ck & 1;
            const int tb  = ck * CHUNK;
            ushort_t A0[8], A1[8], A2[8], Ax[8];
            ushort_t B0[8], B1[8], B2[8], Bx[8];
            LG(A, buf, 0);
            LG(B, buf, 8);
            CG(A, tb, 0);
            LG(A, buf, 16);
            CG(B, tb, 8);
            LG(B, buf, 24);
            CG(A, tb, 16);
            CG(B, tb, 24);
        }
        __syncthreads();
    }

    if (wid == 1) out[(size_t)L_DIM * BD + chain] = c;
}

// ---------- launch ----------
extern "C" void kernel_launch(void* const* d_in, const int* in_sizes, int n_in,
                              void* d_out, int out_size, void* d_ws, size_t ws_size,
                              hipStream_t stream) {
    const float* x      = (const float*)d_in[0];
    const float* weight = (const float*)d_in[1];
    const float* wc     = (const float*)d_in[2];
    const float* bias   = (const float*)d_in[3];
    const float* cinit  = (const float*)d_in[4];
    float* out = (float*)d_out;

    // ws layout (bf16 elems): xb[33554432] | U0|U1|U2 [3*33554432] | wt[786432]
    ushort_t* ws = (ushort_t*)d_ws;
    ushort_t* xb = ws;
    ushort_t* U  = ws + PLANE;           // 3 contiguous planes
    ushort_t* wt = ws + 4 * PLANE;

    k_convert_x<<<4096, 256, 0, stream>>>((const float4*)x, (ushort4*)xb);
    k_prep_w<<<(N_DIM * K_DIM) / 256, 256, 0, stream>>>(weight, wt);
    dim3 grid(N_DIM / 128, M_DIM / 128);   // (12, 512)
    k_gemm<<<grid, 256, 0, stream>>>(xb, wt, bias, U);
    k_scan<<<BD / 64, 128, 0, stream>>>(U, xb, wc, cinit, out);
}